// Round 21
// baseline (63.257 us; speedup 1.0000x reference)
//
#include <hip/hip_runtime.h>
#include <hip/hip_bf16.h>

typedef __hip_bfloat16 bf16;
typedef __attribute__((ext_vector_type(8))) short short8;   // 8 bf16 in 4 VGPRs
typedef __attribute__((ext_vector_type(4))) float f32x4;

#define ED 768
#define NB 8
#define BS 96
#define NH 12
#define HD 64
#define SEQ 2048
#define NBATCH 4
#define NROWS (NBATCH*SEQ)   // 8192

__device__ __forceinline__ float b2f(bf16 v){ return __bfloat162float(v); }
__device__ __forceinline__ bf16 f2b(float v){ return __float2bfloat16(v); }
__device__ __forceinline__ short f2bs(float v){
    return (short)__builtin_bit_cast(unsigned short, __float2bfloat16(v));
}
__device__ __forceinline__ unsigned pkbf16(float lo, float hi){
    return (unsigned)(unsigned short)f2bs(lo) |
           ((unsigned)(unsigned short)f2bs(hi) << 16);
}
__device__ __forceinline__ void gload_lds16(const void* g, void* l) {
    __builtin_amdgcn_global_load_lds(
        (const __attribute__((address_space(1))) unsigned*)g,
        (__attribute__((address_space(3))) unsigned*)l, 16, 0, 0);
}

// ---------------------------------------------------------------------------
// densify_t (validated round 20): LDS-transpose densify, coalesced both ways.
// ---------------------------------------------------------------------------
__global__ __launch_bounds__(256) void densify_t(
    const float* __restrict__ qWv, const float* __restrict__ qWr, const float* __restrict__ qWl,
    const float* __restrict__ kWv, const float* __restrict__ kWr, const float* __restrict__ kWl,
    const float* __restrict__ vWv, const float* __restrict__ vWr, const float* __restrict__ vWl,
    const float* __restrict__ oWv, const float* __restrict__ oWr, const float* __restrict__ oWl,
    bf16* __restrict__ WdBase)
{
    __shared__ __align__(16) bf16 tile[96][104];   // 104 stride: 16B-aligned rows

    const int z = blockIdx.y;
    const float* Wv = (z==0)?qWv:(z==1)?kWv:(z==2)?vWv:oWv;
    const float* Wr = (z==0)?qWr:(z==1)?kWr:(z==2)?vWr:oWr;
    const float* Wl = (z==0)?qWl:(z==1)?kWl:(z==2)?vWl:oWl;
    bf16* Wd = WdBase + (size_t)z*ED*ED;

    const int m = blockIdx.x;            // 0..21
    const float* src; int bt, bs;
    if (m < 8)       { src = Wv + m*96*96;      bt = m;    bs = m;    }
    else if (m < 15) { src = Wr + (m-8)*96*96;  bt = m-7;  bs = m-8;  }
    else             { src = Wl + (m-15)*96*96; bt = m-15; bs = m-14; }

    const int tid = threadIdx.x;
    for (int i = tid; i < 96*96; i += 256) {
        const int ss = i / 96, tt = i - ss*96;
        tile[tt][ss] = f2b(src[i]);
    }
    __syncthreads();
    for (int i = tid; i < 96*12; i += 256) {
        const int tt = i / 12, s8 = (i - tt*12) << 3;
        *(short8*)(Wd + (size_t)(bt*96+tt)*ED + bs*96 + s8) =
            *(const short8*)&tile[tt][s8];
    }
    if (m < 8) {
        const int lo   = (bt == 0) ? 0 : (bt-1)*96;
        const int hi0  = (bt >= 7) ? ED : (bt+2)*96;
        const int zlo8 = lo >> 3;
        const int ztot = zlo8 + ((ED - hi0) >> 3);
        const short8 zz = (short8){0,0,0,0,0,0,0,0};
        for (int i = tid; i < 96*ztot; i += 256) {
            const int tt = i / ztot, q = i - tt*ztot;
            const int col8 = (q < zlo8) ? (q << 3) : (hi0 + ((q - zlo8) << 3));
            *(short8*)(Wd + (size_t)(bt*96+tt)*ED + col8) = zz;
        }
    }
}

// ---------------------------------------------------------------------------
// Fused q/k/v banded GEMM, round 21: T4 counted-vmcnt pipeline.
// B triple-buffered; iteration t stages B(t+2) and the barrier waits only
// vmcnt(N_B) (this wave's just-issued B-gload count: 6 for waves 0-1, 3 for
// waves 2-3) + lgkmcnt(0) — the fresh stage stays in flight across the
// barrier and has a full compute iteration to land. Ordering proof: loads
// newer than B(t+1) at the barrier = {Aload(t+1) (drained by A-write's
// implicit wait), B(t+2)} -> vmcnt(N_B) guarantees B(t+1) complete. Tail
// iteration (no t+2 stage) uses vmcnt(0) (else B(nt-1) could be among the
// N_B newest). sched_barrier(0) pins post-barrier ds_reads (rule #18).
// LDS: 2x8KB A + 3x18KB B = 70KB -> 2 blocks/CU (grid-limited anyway).
// ---------------------------------------------------------------------------
__global__ __launch_bounds__(256, 2) void qkv_gemm_fused(
    const float* __restrict__ x,
    const bf16* __restrict__ WdBase,    // z-strided ED*ED, z=0,1,2
    const float* __restrict__ qb, const float* __restrict__ kb,
    const float* __restrict__ vb,
    bf16* __restrict__ qo, bf16* __restrict__ ko, bf16* __restrict__ vT)
{
    __shared__ __align__(16) bf16 As[2][128*32];      // 8KB each
    __shared__ __align__(16) bf16 Bs[3][3*96*32];     // 18KB each, 3-deep

    const int tid  = threadIdx.x;
    const int lane = tid & 63;
    const int wave = tid >> 6;
    const int rowbase = blockIdx.x*128;
    const int ob = blockIdx.y;
    const int colbase = ob*BS;
    const int klo = (ob==0)    ? 0  : (ob-1)*BS;
    const int khi = (ob==NB-1) ? ED : (ob+2)*BS;
    const int nt  = (khi - klo) >> 5;   // 6 or 9

    // A reg-stage assignment: thread -> row ar, 16-float half ah
    const int ar  = tid >> 1;
    const int ah  = tid & 1;
    const int asw = ((ar & 15) ^ ((ar & 15) >> 2)) & 3;
    const int as0 = ((2*ah)   ^ asw) << 4;
    const int as1 = ((2*ah+1) ^ asw) << 4;
    const float* axbase = x + (size_t)(rowbase + ar)*ED + 16*ah;

    // B gload assignment (per z: 6 x 1KB chunks, 16 rows each)
    const int sub  = lane >> 2;
    const int slot = lane & 3;
    const int sws  = (sub ^ (sub >> 2)) & 3;
    const int kofs = ((slot ^ sws) << 3);

    f32x4 acc[3][2][6];
    #pragma unroll
    for (int z=0;z<3;++z)
        #pragma unroll
        for (int i=0;i<2;++i)
            #pragma unroll
            for (int j=0;j<6;++j) acc[z][i][j] = (f32x4){0.f,0.f,0.f,0.f};

    float4 fr0, fr1, fr2, fr3;
    #define STAGE_A_LOAD(K0) do { \
        const float* ap = axbase + (K0); \
        fr0 = *(const float4*)ap; fr1 = *(const float4*)(ap+4); \
        fr2 = *(const float4*)(ap+8); fr3 = *(const float4*)(ap+12); } while(0)

    #define STAGE_A_WRITE(BUF) do { \
        short8 lo, hi; \
        lo[0]=f2bs(fr0.x); lo[1]=f2bs(fr0.y); lo[2]=f2bs(fr0.z); lo[3]=f2bs(fr0.w); \
        lo[4]=f2bs(fr1.x); lo[5]=f2bs(fr1.y); lo[6]=f2bs(fr1.z); lo[7]=f2bs(fr1.w); \
        hi[0]=f2bs(fr2.x); hi[1]=f2bs(fr2.y); hi[2]=f2bs(fr2.z); hi[3]=f2bs(fr2.w); \
        hi[4]=f2bs(fr3.x); hi[5]=f2bs(fr3.y); hi[6]=f2bs(fr3.z); hi[7]=f2bs(fr3.w); \
        char* abase = (char*)(BUF) + ar*64; \
        *(short8*)(abase + as0) = lo; \
        *(short8*)(abase + as1) = hi; } while(0)

    #define STAGE_B(K0, BUF) do { \
        _Pragma("unroll") \
        for (int zz = 0; zz < 3; ++zz) \
            for (int c = wave; c < 6; c += 4) { \
                const int r = c*16 + sub; \
                gload_lds16(WdBase + (size_t)zz*ED*ED + \
                            (size_t)(colbase + r)*ED + (K0) + kofs, \
                            (char*)(BUF) + zz*6144 + c*1024); \
            } } while(0)

    // counted-vmcnt barrier: allow this wave's freshest B-stage in flight
    #define PIPE_BARRIER_COUNTED() do { \
        if (wave < 2) asm volatile("s_waitcnt vmcnt(6) lgkmcnt(0)" ::: "memory"); \
        else          asm volatile("s_waitcnt vmcnt(3) lgkmcnt(0)" ::: "memory"); \
        __builtin_amdgcn_s_barrier(); \
        __builtin_amdgcn_sched_barrier(0); } while(0)

    #define PIPE_BARRIER_DRAIN() do { \
        asm volatile("s_waitcnt vmcnt(0) lgkmcnt(0)" ::: "memory"); \
        __builtin_amdgcn_s_barrier(); \
        __builtin_amdgcn_sched_barrier(0); } while(0)

    // prologue: A(0) staged; B(0) and B(1) both in flight; wait only for B(0)
    STAGE_A_LOAD(klo);
    STAGE_A_WRITE(As[0]);
    STAGE_B(klo, Bs[0]);
    STAGE_B(klo + 32, Bs[1]);
    PIPE_BARRIER_COUNTED();

    const int l15 = lane & 15;
    const int s   = lane >> 4;
    const int swr = (l15 ^ (l15 >> 2)) & 3;
    const int rsel = ((s ^ swr) << 4);

    #define COMPUTE(BUFA, BUFB) do { \
        short8 a0 = *(const short8*)((const char*)(BUFA) + (wave*32 + l15)*64 + rsel); \
        short8 a1 = *(const short8*)((const char*)(BUFA) + (wave*32 + 16 + l15)*64 + rsel); \
        _Pragma("unroll") \
        for (int zz = 0; zz < 3; ++zz) { \
            short8 b[6]; \
            _Pragma("unroll") \
            for (int nf = 0; nf < 6; ++nf) \
                b[nf] = *(const short8*)((const char*)(BUFB) + zz*6144 + \
                            (nf*16 + l15)*64 + rsel); \
            _Pragma("unroll") \
            for (int nf = 0; nf < 6; ++nf) { \
                acc[zz][0][nf] = __builtin_amdgcn_mfma_f32_16x16x32_bf16(a0, b[nf], acc[zz][0][nf], 0,0,0); \
                acc[zz][1][nf] = __builtin_amdgcn_mfma_f32_16x16x32_bf16(a1, b[nf], acc[zz][1][nf], 0,0,0); \
            } } } while(0)

    int acur = 0, bcur = 0;
    for (int t = 0; t < nt-1; ++t) {
        STAGE_A_LOAD(klo + (t+1)*32);
        const bool more = (t + 2 < nt);
        if (more) {
            int b2 = bcur + 2; if (b2 >= 3) b2 -= 3;
            STAGE_B(klo + (t+2)*32, Bs[b2]);
        }
        COMPUTE(As[acur], Bs[bcur]);
        STAGE_A_WRITE(As[acur^1]);
        if (more) PIPE_BARRIER_COUNTED();
        else      PIPE_BARRIER_DRAIN();
        acur ^= 1;
        if (++bcur == 3) bcur = 0;
    }
    COMPUTE(As[acur], Bs[bcur]);

    // epilogue
    const int rbase = (lane >> 4) * 4;
    const int wrow = rowbase + wave*32;
    #pragma unroll
    for (int zz = 0; zz < 3; ++zz) {
        const float* bias = (zz==0) ? qb : (zz==1) ? kb : vb;
        #pragma unroll
        for (int rf = 0; rf < 2; ++rf) {
            #pragma unroll
            for (int nf = 0; nf < 6; ++nf) {
                const int col = colbase + nf*16 + l15;
                const float bv = bias[col];
                if (zz == 2) {
                    const int row0 = wrow + rf*16 + rbase;
                    uint2 dw;
                    dw.x = pkbf16(acc[2][rf][nf][0] + bv, acc[2][rf][nf][1] + bv);
                    dw.y = pkbf16(acc[2][rf][nf][2] + bv, acc[2][rf][nf][3] + bv);
                    *(uint2*)(vT + ((size_t)(row0 >> 4)*ED + col)*16 + (row0 & 15)) = dw;
                } else {
                    bf16* outp = (zz==0) ? qo : ko;
                    #pragma unroll
                    for (int r = 0; r < 4; ++r) {
                        const int row = wrow + rf*16 + rbase + r;
                        outp[(size_t)row*ED + col] = f2b(acc[zz][rf][nf][r] + bv);
                    }
                }
            }
        }
    }
    #undef STAGE_A_LOAD
    #undef STAGE_A_WRITE
    #undef STAGE_B
    #undef COMPUTE
    #undef PIPE_BARRIER_COUNTED
    #undef PIPE_BARRIER_DRAIN
}

// ---------------------------------------------------------------------------
// LDS-staged banded GEMM for the o-projection (validated rounds 12-20).
// ---------------------------------------------------------------------------
__device__ __forceinline__ void stage64(
    const bf16* __restrict__ Ag, const bf16* __restrict__ Wd,
    int rowbase, int colbase, int k0,
    bf16* As, bf16* Bs, int wave, int lane)
{
    const int r8 = lane >> 3;
    const int sl = lane & 7;
    const int kofs = ((sl ^ r8) << 3);
    #pragma unroll
    for (int c = wave; c < 28; c += 4) {
        if (c < 16) {
            const int row = c*8 + r8;
            gload_lds16(Ag + (size_t)(rowbase + row)*ED + k0 + kofs,
                        (char*)As + c*1024);
        } else {
            const int row = (c-16)*8 + r8;
            gload_lds16(Wd + (size_t)(colbase + row)*ED + k0 + kofs,
                        (char*)Bs + (c-16)*1024);
        }
    }
}

__device__ __forceinline__ void compute64(
    const bf16* As, const bf16* Bs, int wave, int lane, f32x4 acc[2][6])
{
    const int l15 = lane & 15;
    const int s   = lane >> 4;
    #pragma unroll
    for (int ks = 0; ks < 2; ++ks) {
        short8 a[2], b[6];
        #pragma unroll
        for (int rf = 0; rf < 2; ++rf) {
            const int row = wave*32 + rf*16 + l15;
            a[rf] = *(const short8*)((const char*)As + row*128 +
                        ((((ks<<2)+s) ^ (row&7)) << 4));
        }
        #pragma unroll
        for (int nf = 0; nf < 6; ++nf) {
            const int row = nf*16 + l15;
            b[nf] = *(const short8*)((const char*)Bs + row*128 +
                        ((((ks<<2)+s) ^ (row&7)) << 4));
        }
        #pragma unroll
        for (int rf = 0; rf < 2; ++rf)
            #pragma unroll
            for (int nf = 0; nf < 6; ++nf)
                acc[rf][nf] = __builtin_amdgcn_mfma_f32_16x16x32_bf16(
                                  a[rf], b[nf], acc[rf][nf], 0, 0, 0);
    }
}

__device__ __forceinline__ void stage32o(
    const bf16* __restrict__ Ag, const bf16* __restrict__ Wd,
    int rowbase, int colbase, int k0,
    bf16* As, bf16* Bs, int wave, int lane)
{
    const int sub  = lane >> 2;
    const int slot = lane & 3;
    const int sws  = (sub ^ (sub >> 2)) & 3;
    const int kofs = ((slot ^ sws) << 3);
    #pragma unroll
    for (int c = wave; c < 14; c += 4) {
        if (c < 8) {
            const int r = c*16 + sub;
            gload_lds16(Ag + (size_t)(rowbase + r)*ED + k0 + kofs,
                        (char*)As + c*1024);
        } else {
            const int col = (c-8)*16 + sub;
            gload_lds16(Wd + (size_t)(colbase + col)*ED + k0 + kofs,
                        (char*)Bs + (c-8)*1024);
        }
    }
}

__device__ __forceinline__ void compute32o(
    const bf16* As, const bf16* Bs, int wave, int lane, f32x4 acc[2][6])
{
    const int l15 = lane & 15;
    const int s   = lane >> 4;
    const int swr = (l15 ^ (l15 >> 2)) & 3;
    const int rsel = ((s ^ swr) << 4);

    short8 a[2], b[6];
    #pragma unroll
    for (int rf = 0; rf < 2; ++rf)
        a[rf] = *(const short8*)((const char*)As +
                    (wave*32 + rf*16 + l15)*64 + rsel);
    #pragma unroll
    for (int nf = 0; nf < 6; ++nf)
        b[nf] = *(const short8*)((const char*)Bs + (nf*16 + l15)*64 + rsel);
    #pragma unroll
    for (int rf = 0; rf < 2; ++rf)
        #pragma unroll
        for (int nf = 0; nf < 6; ++nf)
            acc[rf][nf] = __builtin_amdgcn_mfma_f32_16x16x32_bf16(
                              a[rf], b[nf], acc[rf][nf], 0, 0, 0);
}

__global__ __launch_bounds__(256, 2) void o_gemm_lds(
    const bf16* __restrict__ A,
    const bf16* __restrict__ Wd,
    const float* __restrict__ bias,
    float* __restrict__ Out)
{
    __shared__ __align__(16) bf16 As[2][128*64];
    __shared__ __align__(16) bf16 Bs[2][96*64];

    const int lane = threadIdx.x & 63;
    const int wave = threadIdx.x >> 6;
    const int rowbase = blockIdx.x*128;
    const int ob = blockIdx.y;
    const int colbase = ob*BS;
    const int klo = (ob==0)    ? 0  : (ob-1)*BS;
    const int khi = (ob==NB-1) ? ED : (ob+2)*BS;
    const int band = khi - klo;
    const int nt64 = band >> 6;
    const bool tail = (band & 63) != 0;

    f32x4 acc[2][6];
    #pragma unroll
    for (int i=0;i<2;++i)
        #pragma unroll
        for (int j=0;j<6;++j) acc[i][j] = (f32x4){0.f,0.f,0.f,0.f};

    stage64(A, Wd, rowbase, colbase, klo, As[0], Bs[0], wave, lane);
    __syncthreads();
    int cur = 0;
    for (int t = 1; t < nt64; ++t) {
        stage64(A, Wd, rowbase, colbase, klo + t*64,
                As[cur^1], Bs[cur^1], wave, lane);
        compute64(As[cur], Bs[cur], wave, lane, acc);
        __syncthreads();
        cur ^= 1;
    }
    if (tail) {
        stage32o(A, Wd, rowbase, colbase, klo + nt64*64,
                 As[cur^1], Bs[cur^1], wave, lane);
        compute64(As[cur], Bs[cur], wave, lane, acc);
        __syncthreads();
        cur ^= 1;
        compute32o(As[cur], Bs[cur], wave, lane, acc);
    } else {
        compute64(As[cur], Bs[cur], wave, lane, acc);
    }

    const int l15 = lane & 15;
    const int rbase = (lane >> 4) * 4;
    const int wrow = rowbase + wave*32;
    #pragma unroll
    for (int rf = 0; rf < 2; ++rf) {
        #pragma unroll
        for (int nf = 0; nf < 6; ++nf) {
            const int col = colbase + nf*16 + l15;
            const float bv = bias[col];
            #pragma unroll
            for (int r = 0; r < 4; ++r) {
                const int row = wrow + rf*16 + rbase + r;
                Out[(size_t)row*ED + col] = acc[rf][nf][r] + bv;
            }
        }
    }
}

// ---------------------------------------------------------------------------
// MFMA sparse attention (round-16/20 validated). Block = 4 consecutive
// q-tiles of one (bb,h); 24-tile K union staged in LDS (48KB); P aliases K
// after barrier 2; V preloaded in VGPRs; XCD-bijective swizzle.
// ---------------------------------------------------------------------------
__global__ __launch_bounds__(256) void sparse_attn_mfma(
    const bf16* __restrict__ q, const bf16* __restrict__ k,
    const bf16* __restrict__ vT, bf16* __restrict__ out)
{
    __shared__ __align__(16) char shm[24*16*128];   // 48KB: Ks, then Plds alias

    const int lane = threadIdx.x & 63;
    const int wid  = threadIdx.x >> 6;
    const int o   = (blockIdx.x & 7)*192 + (blockIdx.x >> 3);
    const int hb  = o >> 5;
    const int qt0 = (o & 31) << 2;
    const int h   = hb % NH;
    const int bb  = hb / NH;
    const int I   = qt0 << 4;
    const int i0  = I + (wid << 4);

    const int l15 = lane & 15;
    const int g   = lane >> 4;

    const bf16* qbase = q + ((size_t)bb*SEQ + i0 + l15)*ED + h*HD + g*8;
    const short8 qf0 = *(const short8*)qbase;
    const short8 qf1 = *(const short8*)(qbase + 32);

    int bases[8];
    bases[0]=i0;     bases[1]=i0-16;  bases[2]=i0-32;  bases[3]=i0-64;
    bases[4]=i0-128; bases[5]=i0-256; bases[6]=i0-512; bases[7]=i0-1024;

    short8 vfrag[4][4];
    #pragma unroll
    for (int u = 0; u < 4; ++u) {
        const int tb = (g & 2) ? bases[2*u+1] : bases[2*u];
        const size_t gt = (size_t)bb*128 + ((tb < 0 ? 0 : tb) >> 4);
        #pragma unroll
        for (int nt = 0; nt < 4; ++nt)
            vfrag[u][nt] = *(const short8*)(vT +
                (gt*ED + h*HD + 16*nt + l15)*16 + 8*(g & 1));
    }

    const bf16* kbb = k + (size_t)bb*SEQ*ED + h*HD;
    #pragma unroll
    for (int c = 0; c < 12; ++c) {
        const int id  = c*256 + threadIdx.x;
        const int row = id >> 3;
        const int sl  = id & 7;
        const int j   = row >> 4;
        int tb;
        if (j < 8) tb = I + 48 - (j << 4);
        else       tb = I + (((j-8) >> 2) << 4) - (128 << ((j-8) & 3));
        const int gr = (tb < 0 ? 0 : tb) + (row & 15);
        gload_lds16(kbb + (size_t)gr*ED + ((sl ^ (row & 7)) << 3),
                    shm + id*16);
    }
    __syncthreads();

    float p[8][4];
    #pragma unroll
    for (int t = 0; t < 8; ++t) {
        const int j = (t < 4) ? ((t == 3 ? 7 : 3 + t) - wid)
                              : (8 + 4*wid + (t - 4));
        f32x4 acc = (f32x4){0.f,0.f,0.f,0.f};
        if (bases[t] >= 0) {
            const char* kr = shm + (j*16 + l15)*128;
            const int sw = l15 & 7;
            const short8 kf0 = *(const short8*)(kr + ((g ^ sw) << 4));
            const short8 kf1 = *(const short8*)(kr + (((g+4) ^ sw) << 4));
            acc = __builtin_amdgcn_mfma_f32_16x16x32_bf16(kf0, qf0, acc, 0,0,0);
            acc = __builtin_amdgcn_mfma_f32_16x16x32_bf16(kf1, qf1, acc, 0,0,0);
        }
        const int Dt = i0 - bases[t];
        #pragma unroll
        for (int r = 0; r < 4; ++r) {
            const int delta = Dt + l15 - 4*g - r;
            const bool val = (bases[t] >= 0) &&
                (((unsigned)delta <= 4u) ||
                 (delta >= 8 && (delta & (delta-1)) == 0));
            p[t][r] = val ? acc[r]*0.125f : -1e30f;   // 1/sqrt(64)
        }
    }

    float m = -1e30f;
    #pragma unroll
    for (int t = 0; t < 8; ++t)
        #pragma unroll
        for (int r = 0; r < 4; ++r) m = fmaxf(m, p[t][r]);
    m = fmaxf(m, __shfl_xor(m, 16));
    m = fmaxf(m, __shfl_xor(m, 32));

    float den = 0.f;
    #pragma unroll
    for (int t = 0; t < 8; ++t)
        #pragma unroll
        for (int r = 0; r < 4; ++r) { p[t][r] = __expf(p[t][r] - m); den += p[t][r]; }
    den += __shfl_xor(den, 16);
    den += __shfl_xor(den, 32);
    const float inv = 1.f / den;

    __syncthreads();

    {
        char* prow = shm + wid*4352 + l15*272;
        #pragma unroll
        for (int t = 0; t < 8; ++t) {
            *(unsigned*)(prow + 32*t + 8*g)     = pkbf16(p[t][0]*inv, p[t][1]*inv);
            *(unsigned*)(prow + 32*t + 8*g + 4) = pkbf16(p[t][2]*inv, p[t][3]*inv);
        }
    }

    f32x4 accO[4];
    #pragma unroll
    for (int nt = 0; nt < 4; ++nt) accO[nt] = (f32x4){0.f,0.f,0.f,0.f};

    #pragma unroll
    for (int u = 0; u < 4; ++u) {
        const short8 pa = *(const short8*)(shm + wid*4352 + l15*272 + 64*u + 16*g);
        #pragma unroll
        for (int nt = 0; nt < 4; ++nt)
            accO[nt] = __builtin_amdgcn_mfma_f32_16x16x32_bf16(
                           pa, vfrag[u][nt], accO[nt], 0,0,0);
    }

    #pragma unroll
    for (int nt = 0; nt < 4; ++nt)
        #pragma unroll
        for (int r = 0; r < 4; ++r)
            out[((size_t)bb*SEQ + i0 + 4*g + r)*ED + h*HD + 16*nt + l15] =
                f2b(accO[nt][r]);
}

// ---------------------------------------------------------------------------
extern "C" void kernel_launch(void* const* d_in, const int* in_sizes, int n_in,
                              void* d_out, int out_size, void* d_ws, size_t ws_size,
                              hipStream_t stream) {
    const float* x   = (const float*)d_in[0];
    const float* qWv = (const float*)d_in[1];
    const float* qWr = (const float*)d_in[2];
    const float* qWl = (const float*)d_in[3];
    const float* qb  = (const float*)d_in[4];
    const float* kWv = (const float*)d_in[5];
    const float* kWr = (const float*)d_in[6];
    const float* kWl = (const float*)d_in[7];
    const float* kb  = (const float*)d_in[8];
    const float* vWv = (const float*)d_in[9];
    const float* vWr = (const float*)d_in[10];
    const float* vWl = (const float*)d_in[11];
    const float* vb  = (const float*)d_in[12];
    const float* oWv = (const float*)d_in[13];
    const float* oWr = (const float*)d_in[14];
    const float* oWl = (const float*)d_in[15];
    const float* ob  = (const float*)d_in[16];
    // d_in[17] = sparse_mask: structural, computed analytically in-kernel.

    const size_t QKV = (size_t)NROWS*ED;   // 6.29M elems
    bf16* q   = (bf16*)d_ws;
    bf16* k   = q + QKV;
    bf16* vT  = k + QKV;                   // v, 16-row-tiled [gtile][col][16]
    bf16* ao  = vT + QKV;
    bf16* Wd  = ao + QKV;                  // 4 x ED*ED (q,k,v,o)
    bf16* Wdo = Wd + (size_t)3*ED*ED;

    densify_t<<<dim3(22, 4), 256, 0, stream>>>(
        qWv,qWr,qWl, kWv,kWr,kWl, vWv,vWr,vWl, oWv,oWr,oWl, Wd);

    qkv_gemm_fused<<<dim3(NROWS/128, NB), 256, 0, stream>>>(
        x, Wd, qb, kb, vb, q, k, vT);

    sparse_attn_mfma<<<(NBATCH*NH*(SEQ/16))/4, 256, 0, stream>>>(q, k, vT, ao);

    o_gemm_lds<<<dim3(NROWS/128, NB), 256, 0, stream>>>(ao, Wdo, ob, (float*)d_out);
}

// Round 22
// 62.945 us; speedup vs baseline: 1.0049x; 1.0049x over previous
//
#include <hip/hip_runtime.h>
#include <hip/hip_bf16.h>

typedef __hip_bfloat16 bf16;
typedef __attribute__((ext_vector_type(8))) short short8;   // 8 bf16 in 4 VGPRs
typedef __attribute__((ext_vector_type(4))) float f32x4;

#define ED 768
#define NB 8
#define BS 96
#define NH 12
#define HD 64
#define SEQ 2048
#define NBATCH 4
#define NROWS (NBATCH*SEQ)   // 8192

__device__ __forceinline__ float b2f(bf16 v){ return __bfloat162float(v); }
__device__ __forceinline__ bf16 f2b(float v){ return __float2bfloat16(v); }
__device__ __forceinline__ short f2bs(float v){
    return (short)__builtin_bit_cast(unsigned short, __float2bfloat16(v));
}
__device__ __forceinline__ unsigned pkbf16(float lo, float hi){
    return (unsigned)(unsigned short)f2bs(lo) |
           ((unsigned)(unsigned short)f2bs(hi) << 16);
}
__device__ __forceinline__ void gload_lds16(const void* g, void* l) {
    __builtin_amdgcn_global_load_lds(
        (const __attribute__((address_space(1))) unsigned*)g,
        (__attribute__((address_space(3))) unsigned*)l, 16, 0, 0);
}

// ---------------------------------------------------------------------------
// densify_t (validated round 20): LDS-transpose densify, coalesced both ways.
// ---------------------------------------------------------------------------
__global__ __launch_bounds__(256) void densify_t(
    const float* __restrict__ qWv, const float* __restrict__ qWr, const float* __restrict__ qWl,
    const float* __restrict__ kWv, const float* __restrict__ kWr, const float* __restrict__ kWl,
    const float* __restrict__ vWv, const float* __restrict__ vWr, const float* __restrict__ vWl,
    const float* __restrict__ oWv, const float* __restrict__ oWr, const float* __restrict__ oWl,
    bf16* __restrict__ WdBase)
{
    __shared__ __align__(16) bf16 tile[96][104];   // 104 stride: 16B-aligned rows

    const int z = blockIdx.y;
    const float* Wv = (z==0)?qWv:(z==1)?kWv:(z==2)?vWv:oWv;
    const float* Wr = (z==0)?qWr:(z==1)?kWr:(z==2)?vWr:oWr;
    const float* Wl = (z==0)?qWl:(z==1)?kWl:(z==2)?vWl:oWl;
    bf16* Wd = WdBase + (size_t)z*ED*ED;

    const int m = blockIdx.x;            // 0..21
    const float* src; int bt, bs;
    if (m < 8)       { src = Wv + m*96*96;      bt = m;    bs = m;    }
    else if (m < 15) { src = Wr + (m-8)*96*96;  bt = m-7;  bs = m-8;  }
    else             { src = Wl + (m-15)*96*96; bt = m-15; bs = m-14; }

    const int tid = threadIdx.x;
    for (int i = tid; i < 96*96; i += 256) {
        const int ss = i / 96, tt = i - ss*96;
        tile[tt][ss] = f2b(src[i]);
    }
    __syncthreads();
    for (int i = tid; i < 96*12; i += 256) {
        const int tt = i / 12, s8 = (i - tt*12) << 3;
        *(short8*)(Wd + (size_t)(bt*96+tt)*ED + bs*96 + s8) =
            *(const short8*)&tile[tt][s8];
    }
    if (m < 8) {
        const int lo   = (bt == 0) ? 0 : (bt-1)*96;
        const int hi0  = (bt >= 7) ? ED : (bt+2)*96;
        const int zlo8 = lo >> 3;
        const int ztot = zlo8 + ((ED - hi0) >> 3);
        const short8 zz = (short8){0,0,0,0,0,0,0,0};
        for (int i = tid; i < 96*ztot; i += 256) {
            const int tt = i / ztot, q = i - tt*ztot;
            const int col8 = (q < zlo8) ? (q << 3) : (hi0 + ((q - zlo8) << 3));
            *(short8*)(Wd + (size_t)(bt*96+tt)*ED + col8) = zz;
        }
    }
}

// ---------------------------------------------------------------------------
// Fused q/k/v banded GEMM (validated rounds 16/21: T4 counted-vmcnt pipeline,
// B triple-buffered; measured equal to the plain 2-phase — kept as-is).
// ---------------------------------------------------------------------------
__global__ __launch_bounds__(256, 2) void qkv_gemm_fused(
    const float* __restrict__ x,
    const bf16* __restrict__ WdBase,    // z-strided ED*ED, z=0,1,2
    const float* __restrict__ qb, const float* __restrict__ kb,
    const float* __restrict__ vb,
    bf16* __restrict__ qo, bf16* __restrict__ ko, bf16* __restrict__ vT)
{
    __shared__ __align__(16) bf16 As[2][128*32];      // 8KB each
    __shared__ __align__(16) bf16 Bs[3][3*96*32];     // 18KB each, 3-deep

    const int tid  = threadIdx.x;
    const int lane = tid & 63;
    const int wave = tid >> 6;
    const int rowbase = blockIdx.x*128;
    const int ob = blockIdx.y;
    const int colbase = ob*BS;
    const int klo = (ob==0)    ? 0  : (ob-1)*BS;
    const int khi = (ob==NB-1) ? ED : (ob+2)*BS;
    const int nt  = (khi - klo) >> 5;   // 6 or 9

    // A reg-stage assignment: thread -> row ar, 16-float half ah
    const int ar  = tid >> 1;
    const int ah  = tid & 1;
    const int asw = ((ar & 15) ^ ((ar & 15) >> 2)) & 3;
    const int as0 = ((2*ah)   ^ asw) << 4;
    const int as1 = ((2*ah+1) ^ asw) << 4;
    const float* axbase = x + (size_t)(rowbase + ar)*ED + 16*ah;

    // B gload assignment (per z: 6 x 1KB chunks, 16 rows each)
    const int sub  = lane >> 2;
    const int slot = lane & 3;
    const int sws  = (sub ^ (sub >> 2)) & 3;
    const int kofs = ((slot ^ sws) << 3);

    f32x4 acc[3][2][6];
    #pragma unroll
    for (int z=0;z<3;++z)
        #pragma unroll
        for (int i=0;i<2;++i)
            #pragma unroll
            for (int j=0;j<6;++j) acc[z][i][j] = (f32x4){0.f,0.f,0.f,0.f};

    float4 fr0, fr1, fr2, fr3;
    #define STAGE_A_LOAD(K0) do { \
        const float* ap = axbase + (K0); \
        fr0 = *(const float4*)ap; fr1 = *(const float4*)(ap+4); \
        fr2 = *(const float4*)(ap+8); fr3 = *(const float4*)(ap+12); } while(0)

    #define STAGE_A_WRITE(BUF) do { \
        short8 lo, hi; \
        lo[0]=f2bs(fr0.x); lo[1]=f2bs(fr0.y); lo[2]=f2bs(fr0.z); lo[3]=f2bs(fr0.w); \
        lo[4]=f2bs(fr1.x); lo[5]=f2bs(fr1.y); lo[6]=f2bs(fr1.z); lo[7]=f2bs(fr1.w); \
        hi[0]=f2bs(fr2.x); hi[1]=f2bs(fr2.y); hi[2]=f2bs(fr2.z); hi[3]=f2bs(fr2.w); \
        hi[4]=f2bs(fr3.x); hi[5]=f2bs(fr3.y); hi[6]=f2bs(fr3.z); hi[7]=f2bs(fr3.w); \
        char* abase = (char*)(BUF) + ar*64; \
        *(short8*)(abase + as0) = lo; \
        *(short8*)(abase + as1) = hi; } while(0)

    #define STAGE_B(K0, BUF) do { \
        _Pragma("unroll") \
        for (int zz = 0; zz < 3; ++zz) \
            for (int c = wave; c < 6; c += 4) { \
                const int r = c*16 + sub; \
                gload_lds16(WdBase + (size_t)zz*ED*ED + \
                            (size_t)(colbase + r)*ED + (K0) + kofs, \
                            (char*)(BUF) + zz*6144 + c*1024); \
            } } while(0)

    // counted-vmcnt barrier: allow this wave's freshest B-stage in flight
    #define PIPE_BARRIER_COUNTED() do { \
        if (wave < 2) asm volatile("s_waitcnt vmcnt(6) lgkmcnt(0)" ::: "memory"); \
        else          asm volatile("s_waitcnt vmcnt(3) lgkmcnt(0)" ::: "memory"); \
        __builtin_amdgcn_s_barrier(); \
        __builtin_amdgcn_sched_barrier(0); } while(0)

    #define PIPE_BARRIER_DRAIN() do { \
        asm volatile("s_waitcnt vmcnt(0) lgkmcnt(0)" ::: "memory"); \
        __builtin_amdgcn_s_barrier(); \
        __builtin_amdgcn_sched_barrier(0); } while(0)

    // prologue: A(0) staged; B(0) and B(1) both in flight; wait only for B(0)
    STAGE_A_LOAD(klo);
    STAGE_A_WRITE(As[0]);
    STAGE_B(klo, Bs[0]);
    STAGE_B(klo + 32, Bs[1]);
    PIPE_BARRIER_COUNTED();

    const int l15 = lane & 15;
    const int s   = lane >> 4;
    const int swr = (l15 ^ (l15 >> 2)) & 3;
    const int rsel = ((s ^ swr) << 4);

    #define COMPUTE(BUFA, BUFB) do { \
        short8 a0 = *(const short8*)((const char*)(BUFA) + (wave*32 + l15)*64 + rsel); \
        short8 a1 = *(const short8*)((const char*)(BUFA) + (wave*32 + 16 + l15)*64 + rsel); \
        _Pragma("unroll") \
        for (int zz = 0; zz < 3; ++zz) { \
            short8 b[6]; \
            _Pragma("unroll") \
            for (int nf = 0; nf < 6; ++nf) \
                b[nf] = *(const short8*)((const char*)(BUFB) + zz*6144 + \
                            (nf*16 + l15)*64 + rsel); \
            _Pragma("unroll") \
            for (int nf = 0; nf < 6; ++nf) { \
                acc[zz][0][nf] = __builtin_amdgcn_mfma_f32_16x16x32_bf16(a0, b[nf], acc[zz][0][nf], 0,0,0); \
                acc[zz][1][nf] = __builtin_amdgcn_mfma_f32_16x16x32_bf16(a1, b[nf], acc[zz][1][nf], 0,0,0); \
            } } } while(0)

    int acur = 0, bcur = 0;
    for (int t = 0; t < nt-1; ++t) {
        STAGE_A_LOAD(klo + (t+1)*32);
        const bool more = (t + 2 < nt);
        if (more) {
            int b2 = bcur + 2; if (b2 >= 3) b2 -= 3;
            STAGE_B(klo + (t+2)*32, Bs[b2]);
        }
        COMPUTE(As[acur], Bs[bcur]);
        STAGE_A_WRITE(As[acur^1]);
        if (more) PIPE_BARRIER_COUNTED();
        else      PIPE_BARRIER_DRAIN();
        acur ^= 1;
        if (++bcur == 3) bcur = 0;
    }
    COMPUTE(As[acur], Bs[bcur]);

    // epilogue
    const int rbase = (lane >> 4) * 4;
    const int wrow = rowbase + wave*32;
    #pragma unroll
    for (int zz = 0; zz < 3; ++zz) {
        const float* bias = (zz==0) ? qb : (zz==1) ? kb : vb;
        #pragma unroll
        for (int rf = 0; rf < 2; ++rf) {
            #pragma unroll
            for (int nf = 0; nf < 6; ++nf) {
                const int col = colbase + nf*16 + l15;
                const float bv = bias[col];
                if (zz == 2) {
                    const int row0 = wrow + rf*16 + rbase;
                    uint2 dw;
                    dw.x = pkbf16(acc[2][rf][nf][0] + bv, acc[2][rf][nf][1] + bv);
                    dw.y = pkbf16(acc[2][rf][nf][2] + bv, acc[2][rf][nf][3] + bv);
                    *(uint2*)(vT + ((size_t)(row0 >> 4)*ED + col)*16 + (row0 & 15)) = dw;
                } else {
                    bf16* outp = (zz==0) ? qo : ko;
                    #pragma unroll
                    for (int r = 0; r < 4; ++r) {
                        const int row = wrow + rf*16 + rbase + r;
                        outp[(size_t)row*ED + col] = f2b(acc[zz][rf][nf][r] + bv);
                    }
                }
            }
        }
    }
    #undef STAGE_A_LOAD
    #undef STAGE_A_WRITE
    #undef STAGE_B
    #undef COMPUTE
    #undef PIPE_BARRIER_COUNTED
    #undef PIPE_BARRIER_DRAIN
}

// ---------------------------------------------------------------------------
// o-projection GEMM, round 22: A (ao, already bf16) reg-staged (4 contiguous
// short8 loads + 4 swizzled ds_write_b128 per thread, no cvt) — only B goes
// through global_load_lds (12 x 1KB chunks per 64-K step, was 28 with A).
// Swizzle involution identical to stage64 (LDS[slot^(row&7)] = global slot),
// so compute64 is unchanged -> bit-identical output. Tail-32 path unchanged.
// ---------------------------------------------------------------------------
__device__ __forceinline__ void compute64(
    const bf16* As, const bf16* Bs, int wave, int lane, f32x4 acc[2][6])
{
    const int l15 = lane & 15;
    const int s   = lane >> 4;
    #pragma unroll
    for (int ks = 0; ks < 2; ++ks) {
        short8 a[2], b[6];
        #pragma unroll
        for (int rf = 0; rf < 2; ++rf) {
            const int row = wave*32 + rf*16 + l15;
            a[rf] = *(const short8*)((const char*)As + row*128 +
                        ((((ks<<2)+s) ^ (row&7)) << 4));
        }
        #pragma unroll
        for (int nf = 0; nf < 6; ++nf) {
            const int row = nf*16 + l15;
            b[nf] = *(const short8*)((const char*)Bs + row*128 +
                        ((((ks<<2)+s) ^ (row&7)) << 4));
        }
        #pragma unroll
        for (int rf = 0; rf < 2; ++rf)
            #pragma unroll
            for (int nf = 0; nf < 6; ++nf)
                acc[rf][nf] = __builtin_amdgcn_mfma_f32_16x16x32_bf16(
                                  a[rf], b[nf], acc[rf][nf], 0, 0, 0);
    }
}

__device__ __forceinline__ void stage32o(
    const bf16* __restrict__ Ag, const bf16* __restrict__ Wd,
    int rowbase, int colbase, int k0,
    bf16* As, bf16* Bs, int wave, int lane)
{
    const int sub  = lane >> 2;
    const int slot = lane & 3;
    const int sws  = (sub ^ (sub >> 2)) & 3;
    const int kofs = ((slot ^ sws) << 3);
    #pragma unroll
    for (int c = wave; c < 14; c += 4) {
        if (c < 8) {
            const int r = c*16 + sub;
            gload_lds16(Ag + (size_t)(rowbase + r)*ED + k0 + kofs,
                        (char*)As + c*1024);
        } else {
            const int col = (c-8)*16 + sub;
            gload_lds16(Wd + (size_t)(colbase + col)*ED + k0 + kofs,
                        (char*)Bs + (c-8)*1024);
        }
    }
}

__device__ __forceinline__ void compute32o(
    const bf16* As, const bf16* Bs, int wave, int lane, f32x4 acc[2][6])
{
    const int l15 = lane & 15;
    const int s   = lane >> 4;
    const int swr = (l15 ^ (l15 >> 2)) & 3;
    const int rsel = ((s ^ swr) << 4);

    short8 a[2], b[6];
    #pragma unroll
    for (int rf = 0; rf < 2; ++rf)
        a[rf] = *(const short8*)((const char*)As +
                    (wave*32 + rf*16 + l15)*64 + rsel);
    #pragma unroll
    for (int nf = 0; nf < 6; ++nf)
        b[nf] = *(const short8*)((const char*)Bs + (nf*16 + l15)*64 + rsel);
    #pragma unroll
    for (int rf = 0; rf < 2; ++rf)
        #pragma unroll
        for (int nf = 0; nf < 6; ++nf)
            acc[rf][nf] = __builtin_amdgcn_mfma_f32_16x16x32_bf16(
                              a[rf], b[nf], acc[rf][nf], 0, 0, 0);
}

__global__ __launch_bounds__(256, 2) void o_gemm_lds(
    const bf16* __restrict__ A,
    const bf16* __restrict__ Wd,
    const float* __restrict__ bias,
    float* __restrict__ Out)
{
    __shared__ __align__(16) bf16 As[2][128*64];   // 16KB each
    __shared__ __align__(16) bf16 Bs[2][96*64];    // 12KB each

    const int tid  = threadIdx.x;
    const int lane = tid & 63;
    const int wave = tid >> 6;
    const int rowbase = blockIdx.x*128;
    const int ob = blockIdx.y;
    const int colbase = ob*BS;
    const int klo = (ob==0)    ? 0  : (ob-1)*BS;
    const int khi = (ob==NB-1) ? ED : (ob+2)*BS;
    const int band = khi - klo;
    const int nt64 = band >> 6;
    const bool tail = (band & 63) != 0;

    // A reg-stage: thread -> row ar (2 threads/row), 32-elem half ah
    const int ar  = tid >> 1;
    const int ah  = tid & 1;
    const int ar7 = ar & 7;
    const bf16* aobase = A + (size_t)(rowbase + ar)*ED + 32*ah;

    // B gload: 12 x 1KB chunks (8 rows each)
    const int r8 = lane >> 3;
    const int sl = lane & 7;
    const int kofsB = ((sl ^ r8) << 3);

    f32x4 acc[2][6];
    #pragma unroll
    for (int i=0;i<2;++i)
        #pragma unroll
        for (int j=0;j<6;++j) acc[i][j] = (f32x4){0.f,0.f,0.f,0.f};

    short8 av0, av1, av2, av3;
    #define OA_LOAD(K0) do { \
        const bf16* ap = aobase + (K0); \
        av0 = *(const short8*)ap;       av1 = *(const short8*)(ap + 8); \
        av2 = *(const short8*)(ap + 16); av3 = *(const short8*)(ap + 24); } while(0)

    #define OA_WRITE(BUF) do { \
        char* ab = (char*)(BUF) + ar*128; \
        *(short8*)(ab + (((4*ah + 0) ^ ar7) << 4)) = av0; \
        *(short8*)(ab + (((4*ah + 1) ^ ar7) << 4)) = av1; \
        *(short8*)(ab + (((4*ah + 2) ^ ar7) << 4)) = av2; \
        *(short8*)(ab + (((4*ah + 3) ^ ar7) << 4)) = av3; } while(0)

    #define OB_STAGE(K0, BUF) do { \
        for (int c = wave; c < 12; c += 4) { \
            const int row = c*8 + r8; \
            gload_lds16(Wd + (size_t)(colbase + row)*ED + (K0) + kofsB, \
                        (char*)(BUF) + c*1024); \
        } } while(0)

    // prologue
    OA_LOAD(klo);
    OB_STAGE(klo, Bs[0]);
    OA_WRITE(As[0]);
    __syncthreads();
    int cur = 0;
    for (int t = 1; t < nt64; ++t) {
        OA_LOAD(klo + t*64);
        OB_STAGE(klo + t*64, Bs[cur^1]);
        compute64(As[cur], Bs[cur], wave, lane, acc);
        OA_WRITE(As[cur^1]);
        __syncthreads();
        cur ^= 1;
    }
    if (tail) {
        stage32o(A, Wd, rowbase, colbase, klo + nt64*64,
                 As[cur^1], Bs[cur^1], wave, lane);
        compute64(As[cur], Bs[cur], wave, lane, acc);
        __syncthreads();
        cur ^= 1;
        compute32o(As[cur], Bs[cur], wave, lane, acc);
    } else {
        compute64(As[cur], Bs[cur], wave, lane, acc);
    }

    const int l15 = lane & 15;
    const int rbase = (lane >> 4) * 4;
    const int wrow = rowbase + wave*32;
    #pragma unroll
    for (int rf = 0; rf < 2; ++rf) {
        #pragma unroll
        for (int nf = 0; nf < 6; ++nf) {
            const int col = colbase + nf*16 + l15;
            const float bv = bias[col];
            #pragma unroll
            for (int r = 0; r < 4; ++r) {
                const int row = wrow + rf*16 + rbase + r;
                Out[(size_t)row*ED + col] = acc[rf][nf][r] + bv;
            }
        }
    }
    #undef OA_LOAD
    #undef OA_WRITE
    #undef OB_STAGE
}

// ---------------------------------------------------------------------------
// MFMA sparse attention (round-16/20 validated). Block = 4 consecutive
// q-tiles of one (bb,h); 24-tile K union staged in LDS (48KB); P aliases K
// after barrier 2; V preloaded in VGPRs; XCD-bijective swizzle.
// ---------------------------------------------------------------------------
__global__ __launch_bounds__(256) void sparse_attn_mfma(
    const bf16* __restrict__ q, const bf16* __restrict__ k,
    const bf16* __restrict__ vT, bf16* __restrict__ out)
{
    __shared__ __align__(16) char shm[24*16*128];   // 48KB: Ks, then Plds alias

    const int lane = threadIdx.x & 63;
    const int wid  = threadIdx.x >> 6;
    const int o   = (blockIdx.x & 7)*192 + (blockIdx.x >> 3);
    const int hb  = o >> 5;
    const int qt0 = (o & 31) << 2;
    const int h   = hb % NH;
    const int bb  = hb / NH;
    const int I   = qt0 << 4;
    const int i0  = I + (wid << 4);

    const int l15 = lane & 15;
    const int g   = lane >> 4;

    const bf16* qbase = q + ((size_t)bb*SEQ + i0 + l15)*ED + h*HD + g*8;
    const short8 qf0 = *(const short8*)qbase;
    const short8 qf1 = *(const short8*)(qbase + 32);

    int bases[8];
    bases[0]=i0;     bases[1]=i0-16;  bases[2]=i0-32;  bases[3]=i0-64;
    bases[4]=i0-128; bases[5]=i0-256; bases[6]=i0-512; bases[7]=i0-1024;

    short8 vfrag[4][4];
    #pragma unroll
    for (int u = 0; u < 4; ++u) {
        const int tb = (g & 2) ? bases[2*u+1] : bases[2*u];
        const size_t gt = (size_t)bb*128 + ((tb < 0 ? 0 : tb) >> 4);
        #pragma unroll
        for (int nt = 0; nt < 4; ++nt)
            vfrag[u][nt] = *(const short8*)(vT +
                (gt*ED + h*HD + 16*nt + l15)*16 + 8*(g & 1));
    }

    const bf16* kbb = k + (size_t)bb*SEQ*ED + h*HD;
    #pragma unroll
    for (int c = 0; c < 12; ++c) {
        const int id  = c*256 + threadIdx.x;
        const int row = id >> 3;
        const int sl  = id & 7;
        const int j   = row >> 4;
        int tb;
        if (j < 8) tb = I + 48 - (j << 4);
        else       tb = I + (((j-8) >> 2) << 4) - (128 << ((j-8) & 3));
        const int gr = (tb < 0 ? 0 : tb) + (row & 15);
        gload_lds16(kbb + (size_t)gr*ED + ((sl ^ (row & 7)) << 3),
                    shm + id*16);
    }
    __syncthreads();

    float p[8][4];
    #pragma unroll
    for (int t = 0; t < 8; ++t) {
        const int j = (t < 4) ? ((t == 3 ? 7 : 3 + t) - wid)
                              : (8 + 4*wid + (t - 4));
        f32x4 acc = (f32x4){0.f,0.f,0.f,0.f};
        if (bases[t] >= 0) {
            const char* kr = shm + (j*16 + l15)*128;
            const int sw = l15 & 7;
            const short8 kf0 = *(const short8*)(kr + ((g ^ sw) << 4));
            const short8 kf1 = *(const short8*)(kr + (((g+4) ^ sw) << 4));
            acc = __builtin_amdgcn_mfma_f32_16x16x32_bf16(kf0, qf0, acc, 0,0,0);
            acc = __builtin_amdgcn_mfma_f32_16x16x32_bf16(kf1, qf1, acc, 0,0,0);
        }
        const int Dt = i0 - bases[t];
        #pragma unroll
        for (int r = 0; r < 4; ++r) {
            const int delta = Dt + l15 - 4*g - r;
            const bool val = (bases[t] >= 0) &&
                (((unsigned)delta <= 4u) ||
                 (delta >= 8 && (delta & (delta-1)) == 0));
            p[t][r] = val ? acc[r]*0.125f : -1e30f;   // 1/sqrt(64)
        }
    }

    float m = -1e30f;
    #pragma unroll
    for (int t = 0; t < 8; ++t)
        #pragma unroll
        for (int r = 0; r < 4; ++r) m = fmaxf(m, p[t][r]);
    m = fmaxf(m, __shfl_xor(m, 16));
    m = fmaxf(m, __shfl_xor(m, 32));

    float den = 0.f;
    #pragma unroll
    for (int t = 0; t < 8; ++t)
        #pragma unroll
        for (int r = 0; r < 4; ++r) { p[t][r] = __expf(p[t][r] - m); den += p[t][r]; }
    den += __shfl_xor(den, 16);
    den += __shfl_xor(den, 32);
    const float inv = 1.f / den;

    __syncthreads();

    {
        char* prow = shm + wid*4352 + l15*272;
        #pragma unroll
        for (int t = 0; t < 8; ++t) {
            *(unsigned*)(prow + 32*t + 8*g)     = pkbf16(p[t][0]*inv, p[t][1]*inv);
            *(unsigned*)(prow + 32*t + 8*g + 4) = pkbf16(p[t][2]*inv, p[t][3]*inv);
        }
    }

    f32x4 accO[4];
    #pragma unroll
    for (int nt = 0; nt < 4; ++nt) accO[nt] = (f32x4){0.f,0.f,0.f,0.f};

    #pragma unroll
    for (int u = 0; u < 4; ++u) {
        const short8 pa = *(const short8*)(shm + wid*4352 + l15*272 + 64*u + 16*g);
        #pragma unroll
        for (int nt = 0; nt < 4; ++nt)
            accO[nt] = __builtin_amdgcn_mfma_f32_16x16x32_bf16(
                           pa, vfrag[u][nt], accO[nt], 0,0,0);
    }

    #pragma unroll
    for (int nt = 0; nt < 4; ++nt)
        #pragma unroll
        for (int r = 0; r < 4; ++r)
            out[((size_t)bb*SEQ + i0 + 4*g + r)*ED + h*HD + 16*nt + l15] =
                f2b(accO[nt][r]);
}

// ---------------------------------------------------------------------------
extern "C" void kernel_launch(void* const* d_in, const int* in_sizes, int n_in,
                              void* d_out, int out_size, void* d_ws, size_t ws_size,
                              hipStream_t stream) {
    const float* x   = (const float*)d_in[0];
    const float* qWv = (const float*)d_in[1];
    const float* qWr = (const float*)d_in[2];
    const float* qWl = (const float*)d_in[3];
    const float* qb  = (const float*)d_in[4];
    const float* kWv = (const float*)d_in[5];
    const float* kWr = (const float*)d_in[6];
    const float* kWl = (const float*)d_in[7];
    const float* kb  = (const float*)d_in[8];
    const float* vWv = (const float*)d_in[9];
    const float* vWr = (const float*)d_in[10];
    const float* vWl = (const float*)d_in[11];
    const float* vb  = (const float*)d_in[12];
    const float* oWv = (const float*)d_in[13];
    const float* oWr = (const float*)d_in[14];
    const float* oWl = (const float*)d_in[15];
    const float* ob  = (const float*)d_in[16];
    // d_in[17] = sparse_mask: structural, computed analytically in-kernel.

    const size_t QKV = (size_t)NROWS*ED;   // 6.29M elems
    bf16* q   = (bf16*)d_ws;
    bf16* k   = q + QKV;
    bf16* vT  = k + QKV;                   // v, 16-row-tiled [gtile][col][16]
    bf16* ao  = vT + QKV;
    bf16* Wd  = ao + QKV;                  // 4 x ED*ED (q,k,v,o)
    bf16* Wdo = Wd + (size_t)3*ED*ED;

    densify_t<<<dim3(22, 4), 256, 0, stream>>>(
        qWv,qWr,qWl, kWv,kWr,kWl, vWv,vWr,vWl, oWv,oWr,oWl, Wd);

    qkv_gemm_fused<<<dim3(NROWS/128, NB), 256, 0, stream>>>(
        x, Wd, qb, kb, vb, q, k, vT);

    sparse_attn_mfma<<<(NBATCH*NH*(SEQ/16))/4, 256, 0, stream>>>(q, k, vT, ao);

    o_gemm_lds<<<dim3(NROWS/128, NB), 256, 0, stream>>>(ao, Wdo, ob, (float*)d_out);
}